// Round 1
// baseline (770.695 us; speedup 1.0000x reference)
//
#include <hip/hip_runtime.h>
#include <math.h>

#define CC 128
#define TWO_C 256
#define NT 8
#define HH 64
#define DD 16
#define LN_EPS 1e-5f

// One wave (64 lanes) per edge; 4 waves per block.
__global__ __launch_bounds__(256) void sheaf_edge_kernel(
    const float* __restrict__ x,          // [N, 128]
    const int*   __restrict__ edge_index, // [2, E]
    const int*   __restrict__ edge_types, // [E]
    const float* __restrict__ gamma,      // [T, 256]
    const float* __restrict__ beta,       // [T, 256]
    const float* __restrict__ W1,         // [T, 256, 64]
    const float* __restrict__ b1,         // [T, 64]
    const float* __restrict__ W2,         // [T, 64, 16]
    const float* __restrict__ b2,         // [T, 16]
    float* __restrict__ out,              // [E, 16]
    int E)
{
    const int wave = threadIdx.x >> 6;
    const int lane = threadIdx.x & 63;
    int e = blockIdx.x * 4 + wave;
    if (e >= E) e = E - 1;  // clamp: redundant recompute, same value written -> benign

    __shared__ float sh[4][TWO_C];   // x_hat (post-affine) per wave
    __shared__ float sh1[4][HH];     // hidden activations per wave

    const int r = edge_index[e];
    const int c = edge_index[E + e];
    const int t = edge_types[e];

    // coalesced gather of h_cat = [x[r], x[c]]
    const float v0 = x[(long)r * CC + lane];
    const float v1 = x[(long)r * CC + 64 + lane];
    const float v2 = x[(long)c * CC + lane];
    const float v3 = x[(long)c * CC + 64 + lane];

    float s  = v0 + v1 + v2 + v3;
    float sq = v0 * v0 + v1 * v1 + v2 * v2 + v3 * v3;
    #pragma unroll
    for (int off = 32; off > 0; off >>= 1) {
        s  += __shfl_xor(s, off);
        sq += __shfl_xor(sq, off);
    }
    const float mu   = s * (1.0f / TWO_C);
    const float var  = sq * (1.0f / TWO_C) - mu * mu;
    const float rstd = rsqrtf(var + LN_EPS);

    const float* gp = gamma + t * TWO_C;
    const float* bp = beta  + t * TWO_C;
    sh[wave][lane]       = (v0 - mu) * rstd * gp[lane]       + bp[lane];
    sh[wave][lane + 64]  = (v1 - mu) * rstd * gp[lane + 64]  + bp[lane + 64];
    sh[wave][lane + 128] = (v2 - mu) * rstd * gp[lane + 128] + bp[lane + 128];
    sh[wave][lane + 192] = (v3 - mu) * rstd * gp[lane + 192] + bp[lane + 192];
    __syncthreads();

    // layer 1: lane i owns hidden unit i. W1 column reads coalesced (stride H across k).
    float h1 = b1[t * HH + lane];
    const float* w1p = W1 + (size_t)t * TWO_C * HH + lane;
    #pragma unroll 8
    for (int k = 0; k < TWO_C; ++k) {
        h1 = fmaf(sh[wave][k], w1p[(size_t)k * HH], h1);
    }
    h1 = fmaxf(h1, 0.0f);
    sh1[wave][lane] = h1;
    __syncthreads();

    if (lane < DD) {
        float o = b2[t * DD + lane];
        const float* w2p = W2 + (size_t)t * HH * DD + lane;
        #pragma unroll 8
        for (int i = 0; i < HH; ++i) {
            o = fmaf(sh1[wave][i], w2p[(size_t)i * DD], o);
        }
        // softmax over groups of 4 lanes (row = lane>>2)
        float m = fmaxf(o, __shfl_xor(o, 1));
        m = fmaxf(m, __shfl_xor(m, 2));
        float p = expf(o - m);
        float ssum = p;
        ssum += __shfl_xor(ssum, 1);
        ssum += __shfl_xor(ssum, 2);
        const float attn = p / ssum;
        const float res = (((lane >> 2) == (lane & 3)) ? 1.0f : 0.0f) - attn;
        out[(size_t)e * DD + lane] = res;
    }
}

extern "C" void kernel_launch(void* const* d_in, const int* in_sizes, int n_in,
                              void* d_out, int out_size, void* d_ws, size_t ws_size,
                              hipStream_t stream) {
    const float* x          = (const float*)d_in[0];
    const int*   edge_index = (const int*)  d_in[1];
    const int*   edge_types = (const int*)  d_in[2];
    const float* gamma      = (const float*)d_in[3];
    const float* beta       = (const float*)d_in[4];
    const float* W1         = (const float*)d_in[5];
    const float* b1         = (const float*)d_in[6];
    const float* W2         = (const float*)d_in[7];
    const float* b2         = (const float*)d_in[8];
    float* out = (float*)d_out;

    const int E = in_sizes[2];
    const int grid = (E + 3) / 4;
    hipLaunchKernelGGL(sheaf_edge_kernel, dim3(grid), dim3(256), 0, stream,
                       x, edge_index, edge_types, gamma, beta, W1, b1, W2, b2, out, E);
}

// Round 2
// 127.947 us; speedup vs baseline: 6.0235x; 6.0235x over previous
//
#include <hip/hip_runtime.h>
#include <math.h>

#define CC 128
#define TWO_C 256
#define NT 8
#define HH 64
#define DD 16
#define LN_EPS 1e-5f

typedef short bf16x8 __attribute__((ext_vector_type(8)));
typedef float f32x4 __attribute__((ext_vector_type(4)));

static __device__ __forceinline__ unsigned short f2bf(float f) {
    union { float f; unsigned int u; } v; v.f = f;
    unsigned int r = (v.u + 0x7fffu + ((v.u >> 16) & 1u)) >> 16;
    return (unsigned short)r;
}

// ---------------- P0: pack W1/W2 to bf16 MFMA-fragment order; zero counts ----
// W1p layout: [t][nt(4)][kt(8)][lane(64)][8]  element = W1[t][kt*32+(l>>4)*8+j][nt*16+(l&15)]
// W2p layout: [t][kt(2)][lane(64)][8]         element = W2[t][kt*32+(l>>4)*8+j][l&15]
__global__ __launch_bounds__(256) void pack_kernel(
    const float* __restrict__ W1, const float* __restrict__ W2,
    unsigned short* __restrict__ W1p, unsigned short* __restrict__ W2p,
    int* __restrict__ counts)
{
    int tid = blockIdx.x * 256 + threadIdx.x;
    if (tid < NT * 4 * 8 * 64) {
        int l = tid & 63, kt = (tid >> 6) & 7, nt = (tid >> 9) & 3, t = tid >> 11;
        int n = nt * 16 + (l & 15);
        int k0 = kt * 32 + (l >> 4) * 8;
        #pragma unroll
        for (int j = 0; j < 8; ++j)
            W1p[tid * 8 + j] = f2bf(W1[(size_t)t * TWO_C * HH + (size_t)(k0 + j) * HH + n]);
    } else if (tid < 16384 + NT * 2 * 64) {
        int s = tid - 16384;
        int l = s & 63, kt = (s >> 6) & 1, t = s >> 7;
        int n = l & 15;
        int k0 = kt * 32 + (l >> 4) * 8;
        #pragma unroll
        for (int j = 0; j < 8; ++j)
            W2p[s * 8 + j] = f2bf(W2[(size_t)t * HH * DD + (size_t)(k0 + j) * DD + n]);
    } else if (tid < 16384 + 1024 + 8) {
        counts[tid - (16384 + 1024)] = 0;
    }
}

// ---------------- P1: histogram of edge types ----------------
__global__ __launch_bounds__(256) void hist_kernel(const int* __restrict__ et,
                                                   int* __restrict__ counts, int E)
{
    __shared__ int lh[NT];
    if (threadIdx.x < NT) lh[threadIdx.x] = 0;
    __syncthreads();
    int i = blockIdx.x * 256 + threadIdx.x;
    if (i < E) atomicAdd(&lh[et[i]], 1);
    __syncthreads();
    if (threadIdx.x < NT && lh[threadIdx.x]) atomicAdd(&counts[threadIdx.x], lh[threadIdx.x]);
}

// ---------------- P2: padded exclusive scan (1 thread) ----------------
__global__ void scan_kernel(const int* __restrict__ counts, int* __restrict__ po,
                            int* __restrict__ cursor)
{
    if (threadIdx.x == 0 && blockIdx.x == 0) {
        int acc = 0;
        for (int t = 0; t < NT; ++t) {
            po[t] = acc;
            cursor[t] = acc;
            acc += ((counts[t] + 63) >> 6) << 6;
        }
        po[NT] = acc;
    }
}

// ---------------- P3: scatter edge ids into type buckets ----------------
__global__ __launch_bounds__(256) void scatter_kernel(const int* __restrict__ et,
                                                      int* __restrict__ cursor,
                                                      int* __restrict__ sorted, int E)
{
    __shared__ int lh[NT], lbase[NT];
    if (threadIdx.x < NT) lh[threadIdx.x] = 0;
    __syncthreads();
    int i = blockIdx.x * 256 + threadIdx.x;
    int t = 0, rank = 0;
    if (i < E) { t = et[i]; rank = atomicAdd(&lh[t], 1); }
    __syncthreads();
    if (threadIdx.x < NT)
        lbase[threadIdx.x] = lh[threadIdx.x] ? atomicAdd(&cursor[threadIdx.x], lh[threadIdx.x]) : 0;
    __syncthreads();
    if (i < E) sorted[lbase[t] + rank] = i;
}

// ---------------- P4: fill padding slots with a valid same-type edge --------
__global__ __launch_bounds__(256) void fill_kernel(const int* __restrict__ counts,
                                                   const int* __restrict__ po,
                                                   int* __restrict__ sorted)
{
    int s = blockIdx.x * 256 + threadIdx.x;
    if (s >= po[NT]) return;
    int t = 0;
    while (s >= po[t + 1]) ++t;
    if (s >= po[t] + counts[t]) sorted[s] = sorted[po[t]];
}

// ---------------- P5: fused gather+LN+GEMM1+ReLU+GEMM2+softmax --------------
// 64 edges (one type) per block, 4 waves. LDS: xhat bf16 swizzled [64][256],
// h1 bf16 [64][72] (144B stride), sorted ids [64].
#define XHAT_OFF 0
#define H1_OFF   32768
#define SID_OFF  (32768 + 9216)
#define LDS_BYTES (32768 + 9216 + 256)

__global__ __launch_bounds__(256) void sheaf_main(
    const float* __restrict__ x, const int* __restrict__ ei,
    const float* __restrict__ gamma, const float* __restrict__ beta,
    const float* __restrict__ b1, const float* __restrict__ b2,
    const unsigned short* __restrict__ W1p, const unsigned short* __restrict__ W2p,
    const int* __restrict__ po, const int* __restrict__ sorted,
    float* __restrict__ out, int E)
{
    __shared__ __align__(16) unsigned char lds[LDS_BYTES];

    const int base = blockIdx.x * 64;
    if (base >= po[NT]) return;
    int t = 0;
    while (base >= po[t + 1]) ++t;

    const int w = threadIdx.x >> 6, lane = threadIdx.x & 63;
    int* sid = (int*)(lds + SID_OFF);
    if (threadIdx.x < 64) sid[threadIdx.x] = sorted[base + threadIdx.x];
    __syncthreads();

    // ---- gather + LN -> xhat bf16 (XOR-swizzled LDS) ----
    const float2 g0  = *(const float2*)(gamma + t * TWO_C + 2 * lane);
    const float2 g1  = *(const float2*)(gamma + t * TWO_C + CC + 2 * lane);
    const float2 be0 = *(const float2*)(beta  + t * TWO_C + 2 * lane);
    const float2 be1 = *(const float2*)(beta  + t * TWO_C + CC + 2 * lane);

    float2 va[16], vb[16];
    #pragma unroll
    for (int i = 0; i < 16; ++i) {
        int e = sid[w * 16 + i];
        int r = ei[e], c = ei[E + e];
        va[i] = *(const float2*)(x + (size_t)r * CC + 2 * lane);
        vb[i] = *(const float2*)(x + (size_t)c * CC + 2 * lane);
    }
    #pragma unroll
    for (int i = 0; i < 16; ++i) {
        float s  = va[i].x + va[i].y + vb[i].x + vb[i].y;
        float sq = va[i].x * va[i].x + va[i].y * va[i].y + vb[i].x * vb[i].x + vb[i].y * vb[i].y;
        #pragma unroll
        for (int off = 32; off > 0; off >>= 1) {
            s  += __shfl_xor(s, off);
            sq += __shfl_xor(sq, off);
        }
        const float mu   = s * (1.0f / TWO_C);
        const float var  = sq * (1.0f / TWO_C) - mu * mu;
        const float rstd = rsqrtf(var + LN_EPS);

        const int row = w * 16 + i;
        const int sw = (row & 7) << 4;
        float h0 = (va[i].x - mu) * rstd * g0.x + be0.x;
        float h1v = (va[i].y - mu) * rstd * g0.y + be0.y;
        float h2 = (vb[i].x - mu) * rstd * g1.x + be1.x;
        float h3 = (vb[i].y - mu) * rstd * g1.y + be1.y;
        unsigned int u0 = (unsigned int)f2bf(h0) | ((unsigned int)f2bf(h1v) << 16);
        unsigned int u1 = (unsigned int)f2bf(h2) | ((unsigned int)f2bf(h3) << 16);
        *(unsigned int*)(lds + XHAT_OFF + row * 512 + ((4 * lane) ^ sw)) = u0;
        *(unsigned int*)(lds + XHAT_OFF + row * 512 + ((256 + 4 * lane) ^ sw)) = u1;
    }
    __syncthreads();

    // ---- GEMM1: [64,256] x [256,64], wave w owns n-tile w ----
    f32x4 acc[4];
    #pragma unroll
    for (int mt = 0; mt < 4; ++mt) acc[mt] = (f32x4){0.f, 0.f, 0.f, 0.f};

    const bf16x8* Bp = (const bf16x8*)W1p + (size_t)((t * 4 + w) * 8) * 64 + lane;
    const int arow = lane & 15;
    const int achunk = (lane >> 4) * 16;
    #pragma unroll
    for (int kt = 0; kt < 8; ++kt) {
        bf16x8 bfrag = Bp[kt * 64];
        #pragma unroll
        for (int mt = 0; mt < 4; ++mt) {
            const int row = mt * 16 + arow;
            bf16x8 afrag = *(const bf16x8*)(lds + XHAT_OFF + row * 512 +
                                            ((kt * 64 + achunk) ^ ((row & 7) << 4)));
            acc[mt] = __builtin_amdgcn_mfma_f32_16x16x32_bf16(afrag, bfrag, acc[mt], 0, 0, 0);
        }
    }

    const float b1v = b1[t * HH + w * 16 + (lane & 15)];
    #pragma unroll
    for (int mt = 0; mt < 4; ++mt) {
        #pragma unroll
        for (int j = 0; j < 4; ++j) {
            float h = fmaxf(acc[mt][j] + b1v, 0.0f);
            int edge = mt * 16 + (lane >> 4) * 4 + j;
            int hid = w * 16 + (lane & 15);
            *(unsigned short*)(lds + H1_OFF + edge * 144 + hid * 2) = f2bf(h);
        }
    }
    __syncthreads();

    // ---- GEMM2: [64,64] x [64,16], wave w owns m-tile w ----
    f32x4 acc2 = (f32x4){0.f, 0.f, 0.f, 0.f};
    #pragma unroll
    for (int kt = 0; kt < 2; ++kt) {
        bf16x8 bfrag = ((const bf16x8*)W2p)[(t * 2 + kt) * 64 + lane];
        int edge = w * 16 + (lane & 15);
        bf16x8 afrag = *(const bf16x8*)(lds + H1_OFF + edge * 144 + kt * 64 + (lane >> 4) * 16);
        acc2 = __builtin_amdgcn_mfma_f32_16x16x32_bf16(afrag, bfrag, acc2, 0, 0, 0);
    }

    const float b2v = b2[t * DD + (lane & 15)];
    const int col = lane & 15;
    const float diag = ((col >> 2) == (col & 3)) ? 1.0f : 0.0f;
    #pragma unroll
    for (int j = 0; j < 4; ++j) {
        float o = acc2[j] + b2v;
        float m = fmaxf(o, __shfl_xor(o, 1));
        m = fmaxf(m, __shfl_xor(m, 2));
        float p = __expf(o - m);
        float su = p + __shfl_xor(p, 1);
        su += __shfl_xor(su, 2);
        float res = diag - p / su;
        int edge = w * 16 + (lane >> 4) * 4 + j;
        int ge = sid[edge];
        out[(size_t)ge * DD + col] = res;
    }
}

extern "C" void kernel_launch(void* const* d_in, const int* in_sizes, int n_in,
                              void* d_out, int out_size, void* d_ws, size_t ws_size,
                              hipStream_t stream) {
    const float* x          = (const float*)d_in[0];
    const int*   edge_index = (const int*)  d_in[1];
    const int*   edge_types = (const int*)  d_in[2];
    const float* gamma      = (const float*)d_in[3];
    const float* beta       = (const float*)d_in[4];
    const float* W1         = (const float*)d_in[5];
    const float* b1         = (const float*)d_in[6];
    const float* W2         = (const float*)d_in[7];
    const float* b2         = (const float*)d_in[8];
    float* out = (float*)d_out;

    const int E = in_sizes[2];

    // workspace layout
    int* ws_i = (int*)d_ws;
    int* counts = ws_i;          // 8
    int* cursor = ws_i + 8;      // 8
    int* po     = ws_i + 16;     // 9
    int* sorted = ws_i + 32;     // E + 512
    size_t w1p_off = ((size_t)(32 + E + 512) * 4 + 255) & ~(size_t)255;
    unsigned short* W1p = (unsigned short*)((char*)d_ws + w1p_off);
    unsigned short* W2p = W1p + (size_t)NT * 4 * 8 * 64 * 8;

    hipLaunchKernelGGL(pack_kernel, dim3(69), dim3(256), 0, stream, W1, W2, W1p, W2p, counts);
    hipLaunchKernelGGL(hist_kernel, dim3((E + 255) / 256), dim3(256), 0, stream,
                       edge_types, counts, E);
    hipLaunchKernelGGL(scan_kernel, dim3(1), dim3(64), 0, stream, counts, po, cursor);
    hipLaunchKernelGGL(scatter_kernel, dim3((E + 255) / 256), dim3(256), 0, stream,
                       edge_types, cursor, sorted, E);
    hipLaunchKernelGGL(fill_kernel, dim3((E + 512 + 255) / 256), dim3(256), 0, stream,
                       counts, po, sorted);
    hipLaunchKernelGGL(sheaf_main, dim3((E + 63) / 64 + NT), dim3(256), 0, stream,
                       x, edge_index, gamma, beta, b1, b2, W1p, W2p, po, sorted, out, E);
}

// Round 3
// 97.011 us; speedup vs baseline: 7.9444x; 1.3189x over previous
//
#include <hip/hip_runtime.h>
#include <math.h>

#define CC 128
#define TWO_C 256
#define NT 8
#define HH 64
#define DD 16

typedef short bf16x8 __attribute__((ext_vector_type(8)));
typedef float f32x4 __attribute__((ext_vector_type(4)));

// exact RNE (used once, in pack)
static __device__ __forceinline__ unsigned short f2bf_rne(float f) {
    union { float f; unsigned int u; } v; v.f = f;
    unsigned int r = (v.u + 0x7fffu + ((v.u >> 16) & 1u)) >> 16;
    return (unsigned short)r;
}
// fast round-half-up pack of two f32 -> u32(bf16 pair)
static __device__ __forceinline__ unsigned int pkbf(float a, float b) {
    unsigned int ua = __float_as_uint(a) + 0x8000u;
    unsigned int ub = __float_as_uint(b) + 0x8000u;
    return (ua >> 16) | (ub & 0xffff0000u);
}

// ---------------- P0: pack W1*gamma / W2 to bf16 frag order; s1,c1; zero counts
// W1p: [t][nt(4)][kt(8)][lane(64)][8]  elem = gamma[t][k]*W1[t][k][n], n=nt*16+(l&15), k=kt*32+(l>>4)*8+j
// W2p: [t][kt(2)][lane(64)][8]         elem = W2[t][kt*32+(l>>4)*8+j][l&15]
__global__ __launch_bounds__(256) void pack_kernel(
    const float* __restrict__ W1, const float* __restrict__ W2,
    const float* __restrict__ gamma, const float* __restrict__ beta,
    const float* __restrict__ b1,
    unsigned short* __restrict__ W1p, unsigned short* __restrict__ W2p,
    float* __restrict__ s1g, float* __restrict__ c1g, int* __restrict__ counts)
{
    int tid = blockIdx.x * 256 + threadIdx.x;
    if (tid < 16384) {
        int l = tid & 63, kt = (tid >> 6) & 7, nt = (tid >> 9) & 3, t = tid >> 11;
        int n = nt * 16 + (l & 15);
        int k0 = kt * 32 + (l >> 4) * 8;
        #pragma unroll
        for (int j = 0; j < 8; ++j) {
            int k = k0 + j;
            float v = gamma[t * TWO_C + k] * W1[(size_t)t * TWO_C * HH + (size_t)k * HH + n];
            W1p[tid * 8 + j] = f2bf_rne(v);
        }
    } else if (tid < 17408) {
        int s = tid - 16384;
        int l = s & 63, kt = (s >> 6) & 1, t = s >> 7;
        int n = l & 15;
        int k0 = kt * 32 + (l >> 4) * 8;
        #pragma unroll
        for (int j = 0; j < 8; ++j)
            W2p[s * 8 + j] = f2bf_rne(W2[(size_t)t * HH * DD + (size_t)(k0 + j) * DD + n]);
    } else if (tid < 17920) {
        int s = tid - 17408;
        int t = s >> 6, n = s & 63;
        float sa = 0.f, ca = 0.f;
        for (int k = 0; k < TWO_C; ++k) {
            float wv = W1[(size_t)t * TWO_C * HH + (size_t)k * HH + n];
            sa = fmaf(gamma[t * TWO_C + k], wv, sa);
            ca = fmaf(beta[t * TWO_C + k], wv, ca);
        }
        s1g[s] = sa;
        c1g[s] = ca + b1[s];
    } else if (tid < 17928) {
        counts[tid - 17920] = 0;
    }
}

// ---------------- P1: histogram (4 edges/thread) ----------------
__global__ __launch_bounds__(256) void hist_kernel(const int* __restrict__ et,
                                                   int* __restrict__ counts, int E)
{
    __shared__ int lh[NT];
    if (threadIdx.x < NT) lh[threadIdx.x] = 0;
    __syncthreads();
    int i0 = (blockIdx.x * 256 + threadIdx.x) * 4;
    #pragma unroll
    for (int j = 0; j < 4; ++j) {
        int i = i0 + j;
        if (i < E) atomicAdd(&lh[et[i]], 1);
    }
    __syncthreads();
    if (threadIdx.x < NT && lh[threadIdx.x]) atomicAdd(&counts[threadIdx.x], lh[threadIdx.x]);
}

// ---------------- P2: padded exclusive scan ----------------
__global__ void scan_kernel(const int* __restrict__ counts, int* __restrict__ po,
                            int* __restrict__ cursor)
{
    if (threadIdx.x == 0 && blockIdx.x == 0) {
        int acc = 0;
        for (int t = 0; t < NT; ++t) {
            po[t] = acc;
            cursor[t] = acc;
            acc += ((counts[t] + 63) >> 6) << 6;
        }
        po[NT] = acc;
    }
}

// ---------------- P3: scatter ids (+ pre-gathered row/col ids) ----------------
__global__ __launch_bounds__(256) void scatter_kernel(const int* __restrict__ et,
                                                      const int* __restrict__ ei,
                                                      int* __restrict__ cursor,
                                                      int* __restrict__ sorted,
                                                      int* __restrict__ srow,
                                                      int* __restrict__ scol,
                                                      int E, int write_rc)
{
    __shared__ int lh[NT], lbase[NT];
    if (threadIdx.x < NT) lh[threadIdx.x] = 0;
    __syncthreads();
    int i0 = (blockIdx.x * 256 + threadIdx.x) * 4;
    int tl[4], rk[4];
    #pragma unroll
    for (int j = 0; j < 4; ++j) {
        int i = i0 + j;
        if (i < E) { tl[j] = et[i]; rk[j] = atomicAdd(&lh[tl[j]], 1); }
    }
    __syncthreads();
    if (threadIdx.x < NT)
        lbase[threadIdx.x] = lh[threadIdx.x] ? atomicAdd(&cursor[threadIdx.x], lh[threadIdx.x]) : 0;
    __syncthreads();
    #pragma unroll
    for (int j = 0; j < 4; ++j) {
        int i = i0 + j;
        if (i < E) {
            int slot = lbase[tl[j]] + rk[j];
            sorted[slot] = i;
            if (write_rc) { srow[slot] = ei[i]; scol[slot] = ei[E + i]; }
        }
    }
}

// ---------------- P4: fill padding slots ----------------
__global__ __launch_bounds__(256) void fill_kernel(const int* __restrict__ counts,
                                                   const int* __restrict__ po,
                                                   int* __restrict__ sorted,
                                                   int* __restrict__ srow,
                                                   int* __restrict__ scol, int write_rc)
{
    int s = blockIdx.x * 256 + threadIdx.x;
    if (s >= po[NT]) return;
    int t = 0;
    while (s >= po[t + 1]) ++t;
    if (s >= po[t] + counts[t]) {
        int src = po[t];
        sorted[s] = sorted[src];
        if (write_rc) { srow[s] = srow[src]; scol[s] = scol[src]; }
    }
}

// ---------------- P5: fused main ----------------
// LDS map (bytes):
//   [0,16384)        xhat half-tile bf16 [64 rows][256B], XOR-swizzled
//   [16384,25600)    h1 bf16 [64][144B]  (rbuf/cbuf aliased at 16384/16640, dead before h1 writes)
//   [25600,26112)    stats float2[64] {mu, rstd}
//   [26112,26368)    sid int[64]
#define XHAT_OFF 0
#define H1_OFF   16384
#define RB_OFF   16384
#define CB_OFF   16640
#define STATS_OFF 25600
#define SID_OFF   26112
#define LDS_BYTES 26368

__global__ __launch_bounds__(256, 6) void sheaf_main(
    const float* __restrict__ x, const int* __restrict__ ei,
    const float* __restrict__ b2,
    const unsigned short* __restrict__ W1p, const unsigned short* __restrict__ W2p,
    const float* __restrict__ s1g, const float* __restrict__ c1g,
    const int* __restrict__ po, const int* __restrict__ sorted,
    const int* __restrict__ srow, const int* __restrict__ scol,
    float* __restrict__ out, int E, int have_rc)
{
    __shared__ __align__(16) unsigned char lds[LDS_BYTES];
    const int base = blockIdx.x * 64;
    if (base >= po[NT]) return;
    int t = 0;
    while (base >= po[t + 1]) ++t;

    const int tid = threadIdx.x;
    const int w = tid >> 6, lane = tid & 63;
    const int lg = lane >> 4, ll = lane & 15;

    int* sid  = (int*)(lds + SID_OFF);
    int* rbuf = (int*)(lds + RB_OFF);
    int* cbuf = (int*)(lds + CB_OFF);

    if (tid < 64) sid[tid] = sorted[base + tid];
    else if (tid < 128 && have_rc) rbuf[tid - 64] = srow[base + tid - 64];
    else if (tid < 192 && have_rc) cbuf[tid - 128] = scol[base + tid - 128];
    __syncthreads();
    if (!have_rc) {
        if (tid < 64) { int e = sid[tid]; rbuf[tid] = ei[e]; cbuf[tid] = ei[E + e]; }
        __syncthreads();
    }

    float s[4] = {0.f, 0.f, 0.f, 0.f}, sq[4] = {0.f, 0.f, 0.f, 0.f};

    // ---- gather half A: x[row] -> bf16 LDS, partial stats ----
    #pragma unroll
    for (int i = 0; i < 4; ++i) {
        const int el = w * 16 + i * 4 + lg;
        const int r = rbuf[el];
        const float4* px = (const float4*)(x + (size_t)r * CC + ll * 8);
        float4 p = px[0], q = px[1];
        s[i] += p.x + p.y + p.z + p.w + q.x + q.y + q.z + q.w;
        sq[i] = fmaf(p.x, p.x, sq[i]); sq[i] = fmaf(p.y, p.y, sq[i]);
        sq[i] = fmaf(p.z, p.z, sq[i]); sq[i] = fmaf(p.w, p.w, sq[i]);
        sq[i] = fmaf(q.x, q.x, sq[i]); sq[i] = fmaf(q.y, q.y, sq[i]);
        sq[i] = fmaf(q.z, q.z, sq[i]); sq[i] = fmaf(q.w, q.w, sq[i]);
        uint4 u;
        u.x = pkbf(p.x, p.y); u.y = pkbf(p.z, p.w);
        u.z = pkbf(q.x, q.y); u.w = pkbf(q.z, q.w);
        *(uint4*)(lds + XHAT_OFF + el * 256 + ((ll * 16) ^ ((el & 7) << 4))) = u;
    }
    __syncthreads();

    // ---- GEMM1 half A (k 0..127) ----
    f32x4 acc[4];
    #pragma unroll
    for (int mt = 0; mt < 4; ++mt) acc[mt] = (f32x4){0.f, 0.f, 0.f, 0.f};
    const bf16x8* Bp = (const bf16x8*)W1p + (size_t)((t * 4 + w) * 8) * 64 + lane;
    #pragma unroll
    for (int kt = 0; kt < 4; ++kt) {
        bf16x8 bfrag = Bp[kt * 64];
        #pragma unroll
        for (int mt = 0; mt < 4; ++mt) {
            int row = mt * 16 + ll;
            bf16x8 afrag = *(const bf16x8*)(lds + XHAT_OFF + row * 256 +
                                            ((kt * 64 + lg * 16) ^ ((row & 7) << 4)));
            acc[mt] = __builtin_amdgcn_mfma_f32_16x16x32_bf16(afrag, bfrag, acc[mt], 0, 0, 0);
        }
    }
    __syncthreads();  // all waves done reading half A

    // ---- gather half B: x[col], finish stats ----
    #pragma unroll
    for (int i = 0; i < 4; ++i) {
        const int el = w * 16 + i * 4 + lg;
        const int c = cbuf[el];
        const float4* px = (const float4*)(x + (size_t)c * CC + ll * 8);
        float4 p = px[0], q = px[1];
        s[i] += p.x + p.y + p.z + p.w + q.x + q.y + q.z + q.w;
        sq[i] = fmaf(p.x, p.x, sq[i]); sq[i] = fmaf(p.y, p.y, sq[i]);
        sq[i] = fmaf(p.z, p.z, sq[i]); sq[i] = fmaf(p.w, p.w, sq[i]);
        sq[i] = fmaf(q.x, q.x, sq[i]); sq[i] = fmaf(q.y, q.y, sq[i]);
        sq[i] = fmaf(q.z, q.z, sq[i]); sq[i] = fmaf(q.w, q.w, sq[i]);
        uint4 u;
        u.x = pkbf(p.x, p.y); u.y = pkbf(p.z, p.w);
        u.z = pkbf(q.x, q.y); u.w = pkbf(q.z, q.w);
        *(uint4*)(lds + XHAT_OFF + el * 256 + ((ll * 16) ^ ((el & 7) << 4))) = u;
    }
    // per-edge stats: butterfly within 16-lane groups (4 edges in parallel)
    #pragma unroll
    for (int i = 0; i < 4; ++i) {
        float s_ = s[i], q_ = sq[i];
        #pragma unroll
        for (int off = 1; off < 16; off <<= 1) {
            s_ += __shfl_xor(s_, off);
            q_ += __shfl_xor(q_, off);
        }
        if (ll == 0) {
            float mu = s_ * (1.0f / TWO_C);
            float var = q_ * (1.0f / TWO_C) - mu * mu;
            float rstd = rsqrtf(var + 1e-5f);
            *(float2*)(lds + STATS_OFF + (w * 16 + i * 4 + lg) * 8) = make_float2(mu, rstd);
        }
    }
    __syncthreads();

    // ---- GEMM1 half B (k 128..255) ----
    #pragma unroll
    for (int kt = 0; kt < 4; ++kt) {
        bf16x8 bfrag = Bp[(4 + kt) * 64];
        #pragma unroll
        for (int mt = 0; mt < 4; ++mt) {
            int row = mt * 16 + ll;
            bf16x8 afrag = *(const bf16x8*)(lds + XHAT_OFF + row * 256 +
                                            ((kt * 64 + lg * 16) ^ ((row & 7) << 4)));
            acc[mt] = __builtin_amdgcn_mfma_f32_16x16x32_bf16(afrag, bfrag, acc[mt], 0, 0, 0);
        }
    }

    // ---- epilogue 1: z = rstd*(acc - mu*s1) + c1, ReLU, bf16 -> h1 LDS ----
    const int n = w * 16 + ll;
    const float s1v = s1g[t * HH + n];
    const float c1v = c1g[t * HH + n];
    #pragma unroll
    for (int mt = 0; mt < 4; ++mt) {
        #pragma unroll
        for (int j = 0; j < 4; ++j) {
            int el = mt * 16 + lg * 4 + j;
            float2 st = *(const float2*)(lds + STATS_OFF + el * 8);
            float z = st.y * (acc[mt][j] - st.x * s1v) + c1v;
            z = fmaxf(z, 0.0f);
            *(unsigned short*)(lds + H1_OFF + el * 144 + n * 2) =
                (unsigned short)((__float_as_uint(z) + 0x8000u) >> 16);
        }
    }
    __syncthreads();

    // ---- GEMM2: [64,64] x [64,16] ----
    f32x4 acc2 = (f32x4){0.f, 0.f, 0.f, 0.f};
    #pragma unroll
    for (int kt = 0; kt < 2; ++kt) {
        bf16x8 bfrag = ((const bf16x8*)W2p)[(t * 2 + kt) * 64 + lane];
        bf16x8 afrag = *(const bf16x8*)(lds + H1_OFF + (w * 16 + ll) * 144 + kt * 64 + lg * 16);
        acc2 = __builtin_amdgcn_mfma_f32_16x16x32_bf16(afrag, bfrag, acc2, 0, 0, 0);
    }

    // ---- softmax rows of 4, out = I - attn ----
    const float b2v = b2[t * DD + ll];
    const float diag = ((ll >> 2) == (ll & 3)) ? 1.0f : 0.0f;
    #pragma unroll
    for (int j = 0; j < 4; ++j) {
        float o = acc2[j] + b2v;
        float m = fmaxf(o, __shfl_xor(o, 1));
        m = fmaxf(m, __shfl_xor(m, 2));
        float p = __expf(o - m);
        float su = p + __shfl_xor(p, 1);
        su += __shfl_xor(su, 2);
        int el = w * 16 + lg * 4 + j;
        int ge = sid[el];
        out[(size_t)ge * DD + ll] = diag - p / su;
    }
}

extern "C" void kernel_launch(void* const* d_in, const int* in_sizes, int n_in,
                              void* d_out, int out_size, void* d_ws, size_t ws_size,
                              hipStream_t stream) {
    const float* x          = (const float*)d_in[0];
    const int*   edge_index = (const int*)  d_in[1];
    const int*   edge_types = (const int*)  d_in[2];
    const float* gamma      = (const float*)d_in[3];
    const float* beta       = (const float*)d_in[4];
    const float* W1         = (const float*)d_in[5];
    const float* b1         = (const float*)d_in[6];
    const float* W2         = (const float*)d_in[7];
    const float* b2         = (const float*)d_in[8];
    float* out = (float*)d_out;

    const int E = in_sizes[2];
    const int cap = E + 512;

    int* ws_i   = (int*)d_ws;
    int* counts = ws_i;          // 8
    int* cursor = ws_i + 8;      // 8
    int* po     = ws_i + 16;     // 9 (padded to 16)
    int* sorted = ws_i + 32;     // cap
    int* srow   = sorted + cap;  // cap (optional)
    int* scol   = srow + cap;    // cap (optional)

    const size_t pack_bytes = (size_t)NT * 4 * 8 * 64 * 8 * 2  // W1p
                            + (size_t)NT * 2 * 64 * 8 * 2      // W2p
                            + (size_t)NT * HH * 4 * 2;         // s1, c1
    const size_t end_norc = (size_t)(32 + cap) * 4;
    const size_t end_rc   = (size_t)(32 + 3 * cap) * 4;
    const int have_rc = (ws_size >= end_rc + 512 + pack_bytes) ? 1 : 0;

    size_t pk_off = ((have_rc ? end_rc : end_norc) + 255) & ~(size_t)255;
    unsigned short* W1p = (unsigned short*)((char*)d_ws + pk_off);
    unsigned short* W2p = W1p + (size_t)NT * 4 * 8 * 64 * 8;
    float* s1g = (float*)(W2p + (size_t)NT * 2 * 64 * 8);
    float* c1g = s1g + NT * HH;

    hipLaunchKernelGGL(pack_kernel, dim3(71), dim3(256), 0, stream,
                       W1, W2, gamma, beta, b1, W1p, W2p, s1g, c1g, counts);
    const int g4 = ((E + 3) / 4 + 255) / 256;
    hipLaunchKernelGGL(hist_kernel, dim3(g4), dim3(256), 0, stream, edge_types, counts, E);
    hipLaunchKernelGGL(scan_kernel, dim3(1), dim3(64), 0, stream, counts, po, cursor);
    hipLaunchKernelGGL(scatter_kernel, dim3(g4), dim3(256), 0, stream,
                       edge_types, edge_index, cursor, sorted, srow, scol, E, have_rc);
    hipLaunchKernelGGL(fill_kernel, dim3((cap + 255) / 256), dim3(256), 0, stream,
                       counts, po, sorted, srow, scol, have_rc);
    hipLaunchKernelGGL(sheaf_main, dim3((E + 63) / 64 + NT), dim3(256), 0, stream,
                       x, edge_index, b2, W1p, W2p, s1g, c1g, po, sorted, srow, scol,
                       out, E, have_rc);
}

// Round 4
// 93.300 us; speedup vs baseline: 8.2604x; 1.0398x over previous
//
#include <hip/hip_runtime.h>
#include <math.h>

#define CC 128
#define TWO_C 256
#define NT 8
#define HH 64
#define DD 16

typedef short bf16x8 __attribute__((ext_vector_type(8)));
typedef float f32x4 __attribute__((ext_vector_type(4)));

// exact RNE (used in weight pack)
static __device__ __forceinline__ unsigned short f2bf_rne(float f) {
    union { float f; unsigned int u; } v; v.f = f;
    unsigned int r = (v.u + 0x7fffu + ((v.u >> 16) & 1u)) >> 16;
    return (unsigned short)r;
}
// fast round-half-up pack of two f32 -> u32(bf16 pair)
static __device__ __forceinline__ unsigned int pkbf(float a, float b) {
    unsigned int ua = __float_as_uint(a) + 0x8000u;
    unsigned int ub = __float_as_uint(b) + 0x8000u;
    return (ua >> 16) | (ub & 0xffff0000u);
}

// ---------------- P0: pack gamma*W1 / W2 bf16 frag order; s1,c1; counts=0; x->bf16
// W1p: [t][nt(4)][kt(8)][lane(64)][8]  elem = gamma[t][k]*W1[t][k][n], n=nt*16+(l&15), k=kt*32+(l>>4)*8+j
// W2p: [t][kt(2)][lane(64)][8]         elem = W2[t][kt*32+(l>>4)*8+j][l&15]
__global__ __launch_bounds__(256) void pack_kernel(
    const float* __restrict__ W1, const float* __restrict__ W2,
    const float* __restrict__ gamma, const float* __restrict__ beta,
    const float* __restrict__ b1, const float* __restrict__ x,
    unsigned short* __restrict__ W1p, unsigned short* __restrict__ W2p,
    float* __restrict__ s1g, float* __restrict__ c1g, int* __restrict__ counts,
    unsigned short* __restrict__ xb, int xtotal)
{
    int tid = blockIdx.x * 256 + threadIdx.x;
    if (tid < 16384) {
        int l = tid & 63, kt = (tid >> 6) & 7, nt = (tid >> 9) & 3, t = tid >> 11;
        int n = nt * 16 + (l & 15);
        int k0 = kt * 32 + (l >> 4) * 8;
        #pragma unroll
        for (int j = 0; j < 8; ++j) {
            int k = k0 + j;
            float v = gamma[t * TWO_C + k] * W1[(size_t)t * TWO_C * HH + (size_t)k * HH + n];
            W1p[tid * 8 + j] = f2bf_rne(v);
        }
    } else if (tid < 17408) {
        int s = tid - 16384;
        int l = s & 63, kt = (s >> 6) & 1, t = s >> 7;
        int n = l & 15;
        int k0 = kt * 32 + (l >> 4) * 8;
        #pragma unroll
        for (int j = 0; j < 8; ++j)
            W2p[s * 8 + j] = f2bf_rne(W2[(size_t)t * HH * DD + (size_t)(k0 + j) * DD + n]);
    } else if (tid < 17920) {
        int s = tid - 17408;
        int t = s >> 6, n = s & 63;
        float sa = 0.f, ca = 0.f;
        for (int k = 0; k < TWO_C; ++k) {
            float wv = W1[(size_t)t * TWO_C * HH + (size_t)k * HH + n];
            sa = fmaf(gamma[t * TWO_C + k], wv, sa);
            ca = fmaf(beta[t * TWO_C + k], wv, ca);
        }
        s1g[s] = sa;
        c1g[s] = ca + b1[s];
    } else if (tid < 17928) {
        counts[tid - 17920] = 0;
    } else {
        int base = (tid - 17928) * 8;
        if (base + 8 <= xtotal) {
            float4 p = *(const float4*)(x + base);
            float4 q = *(const float4*)(x + base + 4);
            uint4 u;
            u.x = pkbf(p.x, p.y); u.y = pkbf(p.z, p.w);
            u.z = pkbf(q.x, q.y); u.w = pkbf(q.z, q.w);
            *(uint4*)(xb + base) = u;
        }
    }
}

// ---------------- P1: histogram (4 edges/thread) ----------------
__global__ __launch_bounds__(256) void hist_kernel(const int* __restrict__ et,
                                                   int* __restrict__ counts, int E)
{
    __shared__ int lh[NT];
    if (threadIdx.x < NT) lh[threadIdx.x] = 0;
    __syncthreads();
    int i0 = (blockIdx.x * 256 + threadIdx.x) * 4;
    if (i0 + 3 < E) {
        int4 tv = *(const int4*)(et + i0);
        atomicAdd(&lh[tv.x], 1); atomicAdd(&lh[tv.y], 1);
        atomicAdd(&lh[tv.z], 1); atomicAdd(&lh[tv.w], 1);
    } else {
        #pragma unroll
        for (int j = 0; j < 4; ++j) {
            int i = i0 + j;
            if (i < E) atomicAdd(&lh[et[i]], 1);
        }
    }
    __syncthreads();
    if (threadIdx.x < NT && lh[threadIdx.x]) atomicAdd(&counts[threadIdx.x], lh[threadIdx.x]);
}

// ---------------- P2: padded exclusive scan ----------------
__global__ void scan_kernel(const int* __restrict__ counts, int* __restrict__ po,
                            int* __restrict__ cursor)
{
    if (threadIdx.x == 0 && blockIdx.x == 0) {
        int acc = 0;
        for (int t = 0; t < NT; ++t) {
            po[t] = acc;
            cursor[t] = acc;
            acc += ((counts[t] + 63) >> 6) << 6;
        }
        po[NT] = acc;
    }
}

// ---------------- P3: scatter ids (+ pre-gathered row/col ids) ----------------
__global__ __launch_bounds__(256) void scatter_kernel(const int* __restrict__ et,
                                                      const int* __restrict__ ei,
                                                      int* __restrict__ cursor,
                                                      int* __restrict__ sorted,
                                                      int* __restrict__ srow,
                                                      int* __restrict__ scol,
                                                      int E, int write_rc)
{
    __shared__ int lh[NT], lbase[NT];
    if (threadIdx.x < NT) lh[threadIdx.x] = 0;
    __syncthreads();
    int i0 = (blockIdx.x * 256 + threadIdx.x) * 4;
    int tl[4], rk[4];
    #pragma unroll
    for (int j = 0; j < 4; ++j) {
        int i = i0 + j;
        if (i < E) { tl[j] = et[i]; rk[j] = atomicAdd(&lh[tl[j]], 1); }
    }
    __syncthreads();
    if (threadIdx.x < NT)
        lbase[threadIdx.x] = lh[threadIdx.x] ? atomicAdd(&cursor[threadIdx.x], lh[threadIdx.x]) : 0;
    __syncthreads();
    #pragma unroll
    for (int j = 0; j < 4; ++j) {
        int i = i0 + j;
        if (i < E) {
            int slot = lbase[tl[j]] + rk[j];
            sorted[slot] = i;
            if (write_rc) { srow[slot] = ei[i]; scol[slot] = ei[E + i]; }
        }
    }
}

// ---------------- P4: fill padding slots ----------------
__global__ __launch_bounds__(256) void fill_kernel(const int* __restrict__ counts,
                                                   const int* __restrict__ po,
                                                   int* __restrict__ sorted,
                                                   int* __restrict__ srow,
                                                   int* __restrict__ scol, int write_rc)
{
    int s = blockIdx.x * 256 + threadIdx.x;
    if (s >= po[NT]) return;
    int t = 0;
    while (s >= po[t + 1]) ++t;
    if (s >= po[t] + counts[t]) {
        int src = po[t];
        sorted[s] = sorted[src];
        if (write_rc) { srow[s] = srow[src]; scol[s] = scol[src]; }
    }
}

// ---------------- P5: fused main ----------------
// LDS map (bytes):
//   [0,16384)       xhat K-half bf16 [64 rows][256B], XOR-swizzled; h1 [64][144B] aliased here
//   [16384,16896)   stats float2[64] {mu,rstd}
//   [16896,17152)   sid int[64]
//   [17152,17408)   rbuf int[64]
//   [17408,17664)   cbuf int[64]
#define XHAT_OFF 0
#define H1_OFF   0
#define STATS_OFF 16384
#define SID_OFF   16896
#define RB_OFF    17152
#define CB_OFF    17408
#define LDS_BYTES 17664

template <int XB>
__global__ __launch_bounds__(256, 8) void sheaf_main(
    const float* __restrict__ x, const unsigned short* __restrict__ xb,
    const int* __restrict__ ei,
    const float* __restrict__ b2,
    const unsigned short* __restrict__ W1p, const unsigned short* __restrict__ W2p,
    const float* __restrict__ s1g, const float* __restrict__ c1g,
    const int* __restrict__ po, const int* __restrict__ sorted,
    const int* __restrict__ srow, const int* __restrict__ scol,
    float* __restrict__ out, int E, int have_rc)
{
    __shared__ __align__(16) unsigned char lds[LDS_BYTES];
    const int base = blockIdx.x * 64;
    if (base >= po[NT]) return;
    int t = 0;
    while (base >= po[t + 1]) ++t;

    const int tid = threadIdx.x;
    const int w = tid >> 6, lane = tid & 63;
    const int lg = lane >> 4, ll = lane & 15;

    int* sid  = (int*)(lds + SID_OFF);
    int* rbuf = (int*)(lds + RB_OFF);
    int* cbuf = (int*)(lds + CB_OFF);

    if (tid < 64) sid[tid] = sorted[base + tid];
    else if (tid < 128 && have_rc) rbuf[tid - 64] = srow[base + tid - 64];
    else if (tid < 192 && have_rc) cbuf[tid - 128] = scol[base + tid - 128];
    __syncthreads();
    if (!have_rc) {
        if (tid < 64) { int e = sid[tid]; rbuf[tid] = ei[e]; cbuf[tid] = ei[E + e]; }
        __syncthreads();
    }

    float s[4] = {0.f, 0.f, 0.f, 0.f}, sq[4] = {0.f, 0.f, 0.f, 0.f};

    // ---- gather half A: row nodes -> bf16 LDS, partial stats ----
    #pragma unroll
    for (int i = 0; i < 4; ++i) {
        const int el = w * 16 + i * 4 + lg;
        const int r = rbuf[el];
        uint4 u;
        if (XB) {
            u = *(const uint4*)(xb + (size_t)r * CC + ll * 8);
            float e0 = __uint_as_float(u.x << 16), e1 = __uint_as_float(u.x & 0xffff0000u);
            float e2 = __uint_as_float(u.y << 16), e3 = __uint_as_float(u.y & 0xffff0000u);
            float e4 = __uint_as_float(u.z << 16), e5 = __uint_as_float(u.z & 0xffff0000u);
            float e6 = __uint_as_float(u.w << 16), e7 = __uint_as_float(u.w & 0xffff0000u);
            s[i] += e0 + e1 + e2 + e3 + e4 + e5 + e6 + e7;
            sq[i] = fmaf(e0, e0, sq[i]); sq[i] = fmaf(e1, e1, sq[i]);
            sq[i] = fmaf(e2, e2, sq[i]); sq[i] = fmaf(e3, e3, sq[i]);
            sq[i] = fmaf(e4, e4, sq[i]); sq[i] = fmaf(e5, e5, sq[i]);
            sq[i] = fmaf(e6, e6, sq[i]); sq[i] = fmaf(e7, e7, sq[i]);
        } else {
            const float4* px = (const float4*)(x + (size_t)r * CC + ll * 8);
            float4 p = px[0], q = px[1];
            s[i] += p.x + p.y + p.z + p.w + q.x + q.y + q.z + q.w;
            sq[i] = fmaf(p.x, p.x, sq[i]); sq[i] = fmaf(p.y, p.y, sq[i]);
            sq[i] = fmaf(p.z, p.z, sq[i]); sq[i] = fmaf(p.w, p.w, sq[i]);
            sq[i] = fmaf(q.x, q.x, sq[i]); sq[i] = fmaf(q.y, q.y, sq[i]);
            sq[i] = fmaf(q.z, q.z, sq[i]); sq[i] = fmaf(q.w, q.w, sq[i]);
            u.x = pkbf(p.x, p.y); u.y = pkbf(p.z, p.w);
            u.z = pkbf(q.x, q.y); u.w = pkbf(q.z, q.w);
        }
        *(uint4*)(lds + XHAT_OFF + el * 256 + ((ll * 16) ^ ((el & 7) << 4))) = u;
    }
    __syncthreads();

    // ---- GEMM1 half A (k 0..127) ----
    f32x4 acc[4];
    #pragma unroll
    for (int mt = 0; mt < 4; ++mt) acc[mt] = (f32x4){0.f, 0.f, 0.f, 0.f};
    const bf16x8* Bp = (const bf16x8*)W1p + (size_t)((t * 4 + w) * 8) * 64 + lane;
    #pragma unroll
    for (int kt = 0; kt < 4; ++kt) {
        bf16x8 bfrag = Bp[kt * 64];
        #pragma unroll
        for (int mt = 0; mt < 4; ++mt) {
            int row = mt * 16 + ll;
            bf16x8 afrag = *(const bf16x8*)(lds + XHAT_OFF + row * 256 +
                                            ((kt * 64 + lg * 16) ^ ((row & 7) << 4)));
            acc[mt] = __builtin_amdgcn_mfma_f32_16x16x32_bf16(afrag, bfrag, acc[mt], 0, 0, 0);
        }
    }
    __syncthreads();  // all waves done reading half A

    // ---- gather half B: col nodes, finish stats ----
    #pragma unroll
    for (int i = 0; i < 4; ++i) {
        const int el = w * 16 + i * 4 + lg;
        const int c = cbuf[el];
        uint4 u;
        if (XB) {
            u = *(const uint4*)(xb + (size_t)c * CC + ll * 8);
            float e0 = __uint_as_float(u.x << 16), e1 = __uint_as_float(u.x & 0xffff0000u);
            float e2 = __uint_as_float(u.y << 16), e3 = __uint_as_float(u.y & 0xffff0000u);
            float e4 = __uint_as_float(u.z << 16), e5 = __uint_as_float(u.z & 0xffff0000u);
            float e6 = __uint_as_float(u.w << 16), e7 = __uint_as_float(u.w & 0xffff0000u);
            s[i] += e0 + e1 + e2 + e3 + e4 + e5 + e6 + e7;
            sq[i] = fmaf(e0, e0, sq[i]); sq[i] = fmaf(e1, e1, sq[i]);
            sq[i] = fmaf(e2, e2, sq[i]); sq[i] = fmaf(e3, e3, sq[i]);
            sq[i] = fmaf(e4, e4, sq[i]); sq[i] = fmaf(e5, e5, sq[i]);
            sq[i] = fmaf(e6, e6, sq[i]); sq[i] = fmaf(e7, e7, sq[i]);
        } else {
            const float4* px = (const float4*)(x + (size_t)c * CC + ll * 8);
            float4 p = px[0], q = px[1];
            s[i] += p.x + p.y + p.z + p.w + q.x + q.y + q.z + q.w;
            sq[i] = fmaf(p.x, p.x, sq[i]); sq[i] = fmaf(p.y, p.y, sq[i]);
            sq[i] = fmaf(p.z, p.z, sq[i]); sq[i] = fmaf(p.w, p.w, sq[i]);
            sq[i] = fmaf(q.x, q.x, sq[i]); sq[i] = fmaf(q.y, q.y, sq[i]);
            sq[i] = fmaf(q.z, q.z, sq[i]); sq[i] = fmaf(q.w, q.w, sq[i]);
            u.x = pkbf(p.x, p.y); u.y = pkbf(p.z, p.w);
            u.z = pkbf(q.x, q.y); u.w = pkbf(q.z, q.w);
        }
        *(uint4*)(lds + XHAT_OFF + el * 256 + ((ll * 16) ^ ((el & 7) << 4))) = u;
    }
    // per-edge stats: butterfly within 16-lane groups
    #pragma unroll
    for (int i = 0; i < 4; ++i) {
        float s_ = s[i], q_ = sq[i];
        #pragma unroll
        for (int off = 1; off < 16; off <<= 1) {
            s_ += __shfl_xor(s_, off);
            q_ += __shfl_xor(q_, off);
        }
        if (ll == 0) {
            float mu = s_ * (1.0f / TWO_C);
            float var = q_ * (1.0f / TWO_C) - mu * mu;
            float rstd = rsqrtf(var + 1e-5f);
            *(float2*)(lds + STATS_OFF + (w * 16 + i * 4 + lg) * 8) = make_float2(mu, rstd);
        }
    }
    __syncthreads();

    // ---- GEMM1 half B (k 128..255) ----
    #pragma unroll
    for (int kt = 0; kt < 4; ++kt) {
        bf16x8 bfrag = Bp[(4 + kt) * 64];
        #pragma unroll
        for (int mt = 0; mt < 4; ++mt) {
            int row = mt * 16 + ll;
            bf16x8 afrag = *(const bf16x8*)(lds + XHAT_OFF + row * 256 +
                                            ((kt * 64 + lg * 16) ^ ((row & 7) << 4)));
            acc[mt] = __builtin_amdgcn_mfma_f32_16x16x32_bf16(afrag, bfrag, acc[mt], 0, 0, 0);
        }
    }
    __syncthreads();  // all waves done with xhat; h1 aliases it

    // ---- epilogue 1: z = rstd*(acc - mu*s1) + c1, ReLU, bf16 -> h1 LDS ----
    const int n = w * 16 + ll;
    const float s1v = s1g[t * HH + n];
    const float c1v = c1g[t * HH + n];
    #pragma unroll
    for (int mt = 0; mt < 4; ++mt) {
        #pragma unroll
        for (int j = 0; j < 4; ++j) {
            int el = mt * 16 + lg * 4 + j;
            float2 st = *(const float2*)(lds + STATS_OFF + el * 8);
            float z = st.y * (acc[mt][j] - st.x * s1v) + c1v;
            z = fmaxf(z, 0.0f);
            *(unsigned short*)(lds + H1_OFF + el * 144 + n * 2) =
                (unsigned short)((__float_as_uint(z) + 0x8000u) >> 16);
        }
    }
    __syncthreads();

    // ---- GEMM2: [64,64] x [64,16] ----
    f32x4 acc2 = (f32x4){0.f, 0.f, 0.f, 0.f};
    #pragma unroll
    for (int kt = 0; kt < 2; ++kt) {
        bf16x8 bfrag = ((const bf16x8*)W2p)[(t * 2 + kt) * 64 + lane];
        bf16x8 afrag = *(const bf16x8*)(lds + H1_OFF + (w * 16 + ll) * 144 + kt * 64 + lg * 16);
        acc2 = __builtin_amdgcn_mfma_f32_16x16x32_bf16(afrag, bfrag, acc2, 0, 0, 0);
    }

    // ---- softmax rows of 4, out = I - attn ----
    const float b2v = b2[t * DD + ll];
    const float diag = ((ll >> 2) == (ll & 3)) ? 1.0f : 0.0f;
    #pragma unroll
    for (int j = 0; j < 4; ++j) {
        float o = acc2[j] + b2v;
        float m = fmaxf(o, __shfl_xor(o, 1));
        m = fmaxf(m, __shfl_xor(m, 2));
        float p = __expf(o - m);
        float su = p + __shfl_xor(p, 1);
        su += __shfl_xor(su, 2);
        int el = w * 16 + lg * 4 + j;
        int ge = sid[el];
        out[(size_t)ge * DD + ll] = diag - p / su;
    }
}

extern "C" void kernel_launch(void* const* d_in, const int* in_sizes, int n_in,
                              void* d_out, int out_size, void* d_ws, size_t ws_size,
                              hipStream_t stream) {
    const float* x          = (const float*)d_in[0];
    const int*   edge_index = (const int*)  d_in[1];
    const int*   edge_types = (const int*)  d_in[2];
    const float* gamma      = (const float*)d_in[3];
    const float* beta       = (const float*)d_in[4];
    const float* W1         = (const float*)d_in[5];
    const float* b1         = (const float*)d_in[6];
    const float* W2         = (const float*)d_in[7];
    const float* b2         = (const float*)d_in[8];
    float* out = (float*)d_out;

    const int E = in_sizes[2];
    const int N = in_sizes[0] / CC;
    const int xtotal = N * CC;
    const int cap = E + 512;

    int* ws_i   = (int*)d_ws;
    int* counts = ws_i;          // 8
    int* cursor = ws_i + 8;      // 8
    int* po     = ws_i + 16;     // 9 (padded to 16)
    int* sorted = ws_i + 32;     // cap
    int* srow   = sorted + cap;  // cap (optional)
    int* scol   = srow + cap;    // cap (optional)

    const size_t pack_bytes = (size_t)NT * 4 * 8 * 64 * 8 * 2  // W1p
                            + (size_t)NT * 2 * 64 * 8 * 2      // W2p
                            + (size_t)NT * HH * 4 * 2;         // s1, c1
    const size_t xb_bytes = (size_t)xtotal * 2;
    const size_t end_norc = (size_t)(32 + cap) * 4;
    const size_t end_rc   = (size_t)(32 + 3 * cap) * 4;
    const int have_rc = (ws_size >= end_rc + 512 + pack_bytes) ? 1 : 0;

    size_t pk_off = ((have_rc ? end_rc : end_norc) + 255) & ~(size_t)255;
    unsigned short* W1p = (unsigned short*)((char*)d_ws + pk_off);
    unsigned short* W2p = W1p + (size_t)NT * 4 * 8 * 64 * 8;
    float* s1g = (float*)(W2p + (size_t)NT * 2 * 64 * 8);
    float* c1g = s1g + NT * HH;

    size_t xb_off = (pk_off + pack_bytes + 255) & ~(size_t)255;
    const int use_xb = (ws_size >= xb_off + xb_bytes) ? 1 : 0;
    unsigned short* xb = (unsigned short*)((char*)d_ws + xb_off);

    const int pack_threads = 17928 + (use_xb ? xtotal / 8 : 0);
    hipLaunchKernelGGL(pack_kernel, dim3((pack_threads + 255) / 256), dim3(256), 0, stream,
                       W1, W2, gamma, beta, b1, x, W1p, W2p, s1g, c1g, counts,
                       xb, use_xb ? xtotal : 0);
    const int g4 = ((E + 3) / 4 + 255) / 256;
    hipLaunchKernelGGL(hist_kernel, dim3(g4), dim3(256), 0, stream, edge_types, counts, E);
    hipLaunchKernelGGL(scan_kernel, dim3(1), dim3(64), 0, stream, counts, po, cursor);
    hipLaunchKernelGGL(scatter_kernel, dim3(g4), dim3(256), 0, stream,
                       edge_types, edge_index, cursor, sorted, srow, scol, E, have_rc);
    hipLaunchKernelGGL(fill_kernel, dim3((cap + 255) / 256), dim3(256), 0, stream,
                       counts, po, sorted, srow, scol, have_rc);
    const int gmain = (E + 63) / 64 + NT;
    if (use_xb)
        hipLaunchKernelGGL(sheaf_main<1>, dim3(gmain), dim3(256), 0, stream,
                           x, xb, edge_index, b2, W1p, W2p, s1g, c1g, po, sorted, srow, scol,
                           out, E, have_rc);
    else
        hipLaunchKernelGGL(sheaf_main<0>, dim3(gmain), dim3(256), 0, stream,
                           x, xb, edge_index, b2, W1p, W2p, s1g, c1g, po, sorted, srow, scol,
                           out, E, have_rc);
}